// Round 2
// baseline (449.803 us; speedup 1.0000x reference)
//
#include <hip/hip_runtime.h>
#include <math.h>

typedef __attribute__((ext_vector_type(8))) short short8;
typedef __attribute__((ext_vector_type(4))) float f32x4;
typedef unsigned short u16;

#define DEV static __device__ __forceinline__

DEV u16 f2bf(float f) {
  union { float f; unsigned u; } v; v.f = f;
  unsigned r = v.u + 0x7FFFu + ((v.u >> 16) & 1u);
  return (u16)(r >> 16);
}
DEV float bf2f(u16 u) {
  union { unsigned u; float f; } v; v.u = ((unsigned)u) << 16;
  return v.f;
}

// ---------------- K0: convert weights to bf16 ----------------
__global__ __launch_bounds__(256) void k_conv(const float* __restrict__ W,
                                              const float* __restrict__ Wf,
                                              u16* __restrict__ Wb,
                                              u16* __restrict__ Wfb) {
  int i = (blockIdx.x * 256 + threadIdx.x) * 4;
  const int NW = 1024 * 1024;
  if (i < NW) {
    float4 v = *(const float4*)(W + i);
    ushort4 o = {f2bf(v.x), f2bf(v.y), f2bf(v.z), f2bf(v.w)};
    *(ushort4*)(Wb + i) = o;
  } else {
    int j = i - NW;  // < 65536
    float4 v = *(const float4*)(Wf + j);
    ushort4 o = {f2bf(v.x), f2bf(v.y), f2bf(v.z), f2bf(v.w)};
    *(ushort4*)(Wfb + j) = o;
  }
}

// ---------------- K1: z = cos(x + a0[d]) * cos(a1[d]), bf16 ----------------
__global__ __launch_bounds__(256) void k_zenc(const float* __restrict__ x,
                                              const float* __restrict__ qp, // [64][3]
                                              u16* __restrict__ z) {
  __shared__ float a0[64], c1[64];
  int t = threadIdx.x;
  if (t < 64) { a0[t] = qp[t * 3]; c1[t] = cosf(qp[t * 3 + 1]); }
  __syncthreads();
  size_t i = ((size_t)blockIdx.x * 256 + t) * 4;
  float4 xv = *(const float4*)(x + i);
  int d = (int)(i & 63);
  ushort4 o;
  o.x = f2bf(cosf(xv.x + a0[d + 0]) * c1[d + 0]);
  o.y = f2bf(cosf(xv.y + a0[d + 1]) * c1[d + 1]);
  o.z = f2bf(cosf(xv.z + a0[d + 2]) * c1[d + 2]);
  o.w = f2bf(cosf(xv.w + a0[d + 3]) * c1[d + 3]);
  *(ushort4*)(z + i) = o;
}

// ---------- K2: fused  Y = Z @ W^T + x + b ;  X1 = LN1(Y) ; Q = enc(X1) ----
// BM=64 rows x BN=1024 (full row) per WG, BK=32, 8 waves (512 thr), 256 WGs.
// X1 written bf16 IN-PLACE over Z's rows (rows are WG-exclusive).
__global__ __launch_bounds__(512) void k_gemm_ln1(
    const u16* __restrict__ Z, const u16* __restrict__ Wb,
    const float* __restrict__ x, const float* __restrict__ opb,
    const float* __restrict__ w1, const float* __restrict__ b1,
    const float* __restrict__ fqp,
    u16* __restrict__ X1, u16* __restrict__ Q) {
  constexpr int K = 1024;
  __shared__ __attribute__((aligned(16))) u16 As[2][64 * 32];     // 8 KB
  __shared__ __attribute__((aligned(16))) u16 Bs[2][1024 * 32];   // 128 KB
  __shared__ float redS[64][8];
  __shared__ float redQ[64][8];
  __shared__ float muF[64], rsF[64];

  int t = threadIdx.x, lane = t & 63, wv = t >> 6;
  int m0 = blockIdx.x * 64;

  const u16* gA = Z + (size_t)(m0 + (t >> 2)) * K + (t & 3) * 8;
  const u16* gB = Wb + (size_t)(t >> 2) * K + (t & 3) * 8;

  auto stage = [&](int buf, int kt) {
    int ko = kt * 32;
    if (t < 256) {  // waves 0-3 stage A (64x32)
      __builtin_amdgcn_global_load_lds(
          (const __attribute__((address_space(1))) unsigned int*)(gA + ko),
          (__attribute__((address_space(3))) unsigned int*)&As[buf][wv * 512],
          16, 0, 0);
    }
#pragma unroll
    for (int j = 0; j < 8; ++j) {  // all 8 waves stage B (1024x32)
      __builtin_amdgcn_global_load_lds(
          (const __attribute__((address_space(1))) unsigned int*)(gB + (size_t)j * 128 * K + ko),
          (__attribute__((address_space(3))) unsigned int*)&Bs[buf][j * 4096 + wv * 512],
          16, 0, 0);
    }
  };

  f32x4 acc[4][8];
#pragma unroll
  for (int m = 0; m < 4; ++m)
#pragma unroll
    for (int n = 0; n < 8; ++n) acc[m][n] = (f32x4){0.f, 0.f, 0.f, 0.f};

  stage(0, 0);
  int cur = 0;
  int kof = (lane >> 4) * 8;
  int cl = lane & 15;
  for (int kt = 0; kt < K / 32; ++kt) {
    __syncthreads();  // drains vmcnt -> buf[cur] landed; prev reads done
    if (kt + 1 < K / 32) stage(cur ^ 1, kt + 1);
    short8 av[4], bv[8];
#pragma unroll
    for (int m = 0; m < 4; ++m)
      av[m] = *(const short8*)&As[cur][(m * 16 + cl) * 32 + kof];
#pragma unroll
    for (int n = 0; n < 8; ++n)
      bv[n] = *(const short8*)&Bs[cur][(wv * 128 + n * 16 + cl) * 32 + kof];
#pragma unroll
    for (int m = 0; m < 4; ++m)
#pragma unroll
      for (int n = 0; n < 8; ++n)
        acc[m][n] = __builtin_amdgcn_mfma_f32_16x16x32_bf16(av[m], bv[n], acc[m][n], 0, 0, 0);
    cur ^= 1;
  }

  // ---- epilogue: residual + bias, LN1 stats, normalize, X1 + Q ----
  int rbase = (lane >> 4) * 4;  // C-frag row group (m89-verified layout)
  float w1c[8], b1c[8];
#pragma unroll
  for (int n = 0; n < 8; ++n) {
    int col = wv * 128 + n * 16 + cl;
    w1c[n] = w1[col];
    b1c[n] = b1[col];
  }
  float rowS[16], rowQ2[16];
#pragma unroll
  for (int i = 0; i < 16; ++i) { rowS[i] = 0.f; rowQ2[i] = 0.f; }
#pragma unroll
  for (int m = 0; m < 4; ++m) {
#pragma unroll
    for (int n = 0; n < 8; ++n) {
      int col = wv * 128 + n * 16 + cl;
      float bias = opb[col];
#pragma unroll
      for (int r = 0; r < 4; ++r) {
        int row = m * 16 + rbase + r;
        float v = acc[m][n][r] + x[(size_t)(m0 + row) * 1024 + col] + bias;
        acc[m][n][r] = v;
        rowS[m * 4 + r] += v;
        rowQ2[m * 4 + r] += v * v;
      }
    }
  }
#pragma unroll
  for (int i = 0; i < 16; ++i) {
#pragma unroll
    for (int msk = 1; msk < 16; msk <<= 1) {
      rowS[i] += __shfl_xor(rowS[i], msk, 64);
      rowQ2[i] += __shfl_xor(rowQ2[i], msk, 64);
    }
  }
  if (cl == 0) {
#pragma unroll
    for (int m = 0; m < 4; ++m)
#pragma unroll
      for (int r = 0; r < 4; ++r) {
        int row = m * 16 + rbase + r;
        redS[row][wv] = rowS[m * 4 + r];
        redQ[row][wv] = rowQ2[m * 4 + r];
      }
  }
  __syncthreads();
  if (t < 64) {
    float s = 0.f, q = 0.f;
#pragma unroll
    for (int w = 0; w < 8; ++w) { s += redS[t][w]; q += redQ[t][w]; }
    float mu = s * (1.f / 1024.f);
    float var = q * (1.f / 1024.f) - mu * mu;
    muF[t] = mu;
    rsF[t] = rsqrtf(var + 1e-5f);
  }
  __syncthreads();
#pragma unroll
  for (int m = 0; m < 4; ++m) {
#pragma unroll
    for (int r = 0; r < 4; ++r) {
      int row = m * 16 + rbase + r;
      float mu = muF[row], rs = rsF[row];
#pragma unroll
      for (int n = 0; n < 8; ++n) {
        int col = wv * 128 + n * 16 + cl;
        float x1 = (acc[m][n][r] - mu) * rs * w1c[n] + b1c[n];
        X1[(size_t)(m0 + row) * 1024 + col] = f2bf(x1);
        if (wv == 0 && n < 4) {  // cols 0-63: quantum FFN encoder input
          float qv = cosf(x1 + fqp[col * 3]) * cosf(fqp[col * 3 + 1]);
          Q[(size_t)(m0 + row) * 64 + col] = f2bf(qv);
        }
      }
    }
  }
}

// ---------------- K3: ffn = Q @ Wf^T; out = LN2(x1 + ffn + fb) ------------
__global__ __launch_bounds__(256) void k_ffn(const u16* __restrict__ X1,
                                             const u16* __restrict__ Q,
                                             const u16* __restrict__ Wfb,
                                             const float* __restrict__ fb,
                                             const float* __restrict__ w2,
                                             const float* __restrict__ b2,
                                             float* __restrict__ out) {
  __shared__ float t2[16][1024];  // 64 KB
  int t = threadIdx.x, lane = t & 63, wv = t >> 6;
  int m0 = blockIdx.x * 16;
  int kof = (lane >> 4) * 8;
  const short8 a0v = *(const short8*)&Q[(size_t)(m0 + (lane & 15)) * 64 + kof];
  const short8 a1v = *(const short8*)&Q[(size_t)(m0 + (lane & 15)) * 64 + 32 + kof];
  int nbase = wv * 256;
#pragma unroll
  for (int ni = 0; ni < 16; ++ni) {
    int n = nbase + ni * 16 + (lane & 15);
    short8 b0 = *(const short8*)&Wfb[(size_t)n * 64 + kof];
    short8 b1 = *(const short8*)&Wfb[(size_t)n * 64 + 32 + kof];
    f32x4 acc = (f32x4){0.f, 0.f, 0.f, 0.f};
    acc = __builtin_amdgcn_mfma_f32_16x16x32_bf16(a0v, b0, acc, 0, 0, 0);
    acc = __builtin_amdgcn_mfma_f32_16x16x32_bf16(a1v, b1, acc, 0, 0, 0);
#pragma unroll
    for (int r = 0; r < 4; ++r) t2[(lane >> 4) * 4 + r][n] = acc[r];
  }
  __syncthreads();
  for (int rr = 0; rr < 4; ++rr) {
    int row = wv * 4 + rr;
    size_t grow = (size_t)(m0 + row) * 1024;
    float vv[16];
    float s = 0.f, s2 = 0.f;
#pragma unroll
    for (int j = 0; j < 16; ++j) {
      int col = j * 64 + lane;
      float val = bf2f(X1[grow + col]) + t2[row][col] + fb[col];
      vv[j] = val; s += val; s2 += val * val;
    }
#pragma unroll
    for (int m = 1; m < 64; m <<= 1) { s += __shfl_xor(s, m, 64); s2 += __shfl_xor(s2, m, 64); }
    float mu = s * (1.f / 1024.f);
    float var = s2 * (1.f / 1024.f) - mu * mu;
    float rs = rsqrtf(var + 1e-5f);
#pragma unroll
    for (int j = 0; j < 16; ++j) {
      int col = j * 64 + lane;
      out[grow + col] = (vv[j] - mu) * rs * w2[col] + b2[col];
    }
  }
}

extern "C" void kernel_launch(void* const* d_in, const int* in_sizes, int n_in,
                              void* d_out, int out_size, void* d_ws, size_t ws_size,
                              hipStream_t stream) {
  const float* x   = (const float*)d_in[0];
  const float* aqp = (const float*)d_in[1];
  const float* opw = (const float*)d_in[2];
  const float* opb = (const float*)d_in[3];
  const float* fqp = (const float*)d_in[4];
  const float* flw = (const float*)d_in[5];
  const float* flb = (const float*)d_in[6];
  const float* n1w = (const float*)d_in[7];
  const float* n1b = (const float*)d_in[8];
  const float* n2w = (const float*)d_in[9];
  const float* n2b = (const float*)d_in[10];
  float* out = (float*)d_out;

  char* ws = (char*)d_ws;
  u16* zbuf = (u16*)(ws + 0);          // Z (bf16), becomes X1 in-place
  u16* Wb   = (u16*)(ws + 33554432);   // 1024x1024 bf16
  u16* Wfb  = (u16*)(ws + 35651584);   // 1024x64 bf16
  u16* Qb   = (u16*)(ws + 35782656);   // 16384x64 bf16

  k_conv<<<1088, 256, 0, stream>>>(opw, flw, Wb, Wfb);
  k_zenc<<<16384, 256, 0, stream>>>(x, aqp, zbuf);
  k_gemm_ln1<<<256, 512, 0, stream>>>(zbuf, Wb, x, opb, n1w, n1b, fqp,
                                      zbuf /*X1 in-place*/, Qb);
  k_ffn<<<1024, 256, 0, stream>>>(zbuf, Qb, Wfb, flb, n2w, n2b, out);
}